// Round 8
// baseline (63.493 us; speedup 1.0000x reference)
//
#include <hip/hip_runtime.h>

// out[b,t,c] = x[b,t,c] + sum_{s=max(t-8,0)}^{t-1} isi[b,s,c]
// isi[..., f]    = h[f]*x[f]   - h[f+64]*x[f+64]   (f < 64)
// isi[..., f+64] = h[f]*x[f+64] + h[f+64]*x[f]
//
// B=32, T=8192, C=128, W=8.
// LDS-handoff version: workgroup = 4 waves = 8 half-wave columns covering 8
// CONSECUTIVE chunks (TC=64) of one batch. Phase A: each column pre-reads its
// own last 8 timesteps (data it owns anyway), computes isi, stores isi to its
// LDS slot, keeps x & isi in registers. Barrier. Phase B: column k inits its
// window ring from column k-1's LDS slot (global warm-up only for k==0 ->
// warm-up redundancy 12.5% -> 1.2%). Phase C: 56 normal streamed steps.
// Phase D: last 8 steps from registers (no loads). Demand ~388 MB vs the
// 384 MB compulsory floor; at the 6.3 TB/s demand ceiling -> ~61.6 us.

typedef float f2 __attribute__((ext_vector_type(2)));

constexpr int TLEN   = 8192;
constexpr int CCH    = 128;
constexpr int FHALF  = 64;
constexpr int WWIN   = 8;
constexpr int TC     = 64;            // timesteps per column-chunk
constexpr int NCHUNK = TLEN / TC;     // 128
constexpr int NB     = 32;
constexpr int CPG    = 8;             // columns (chunks) per workgroup

__global__ __launch_bounds__(256) void isi_window_kernel(
    const float* __restrict__ x, const float* __restrict__ h,
    float* __restrict__ out)
{
    __shared__ float lds[CPG][WWIN][CCH];             // isi tails, 32 KB

    const int wave = threadIdx.x >> 6;
    const int lane = threadIdx.x & 63;
    const int c2   = (lane & 31) * 2;                 // first channel of the pair-of-pairs
    const int half = lane >> 5;
    const int k    = wave * 2 + half;                 // column slot in wg, 0..7

    const int col   = blockIdx.x * CPG + k;           // 0 .. 4095 (= b*NCHUNK + chunk)
    const int b     = col >> 7;                       // col / NCHUNK
    const int chunk = col & (NCHUNK - 1);
    const int t0    = chunk * TC;

    const size_t base = (size_t)b * TLEN * CCH + c2;
    const float* xb = x + base;
    const float* hb = h + base;
    float*       ob = out + base;

    // ---- Phase A: pre-read own tail (last 8 steps), compute isi, share via LDS,
    //      keep x and isi in registers for Phase D.
    f2 xtr[WWIN], xti[WWIN], itr[WWIN], iti[WWIN];
#pragma unroll
    for (int j = 0; j < WWIN; ++j) {
        const size_t off = (size_t)(t0 + TC - WWIN + j) * CCH;
        const f2 xr = *(const f2*)(xb + off);
        const f2 xi = *(const f2*)(xb + off + FHALF);
        const f2 hr = *(const f2*)(hb + off);
        const f2 hi = *(const f2*)(hb + off + FHALF);
        const f2 ir = hr * xr - hi * xi;
        const f2 ii = hr * xi + hi * xr;
        xtr[j] = xr; xti[j] = xi; itr[j] = ir; iti[j] = ii;
        *(f2*)&lds[k][j][c2]         = ir;
        *(f2*)&lds[k][j][FHALF + c2] = ii;
    }
    __syncthreads();

    // ---- Phase B: initialize window ring (isi of the 8 steps before t0).
    f2 histr[WWIN], histi[WWIN];
    f2 winr = (f2)(0.f), wini = (f2)(0.f);
    if (k > 0) {
#pragma unroll
        for (int j = 0; j < WWIN; ++j) {
            const f2 ir = *(const f2*)&lds[k - 1][j][c2];
            const f2 ii = *(const f2*)&lds[k - 1][j][FHALF + c2];
            histr[j] = ir; histi[j] = ii;
            winr += ir; wini += ii;
        }
    } else if (chunk > 0) {
#pragma unroll
        for (int j = 0; j < WWIN; ++j) {
            const size_t off = (size_t)(t0 - WWIN + j) * CCH;
            const f2 xr = *(const f2*)(xb + off);
            const f2 xi = *(const f2*)(xb + off + FHALF);
            const f2 hr = *(const f2*)(hb + off);
            const f2 hi = *(const f2*)(hb + off + FHALF);
            const f2 ir = hr * xr - hi * xi;
            const f2 ii = hr * xi + hi * xr;
            histr[j] = ir; histi[j] = ii;
            winr += ir; wini += ii;
        }
    } else {
#pragma unroll
        for (int j = 0; j < WWIN; ++j) {
            histr[j] = (f2)(0.f);
            histi[j] = (f2)(0.f);
        }
    }

    // ---- Phase C: streamed main loop over [t0, t0+TC-8).
    for (int tb = t0; tb < t0 + TC - WWIN; tb += WWIN) {
#pragma unroll
        for (int j = 0; j < WWIN; ++j) {
            const size_t off = (size_t)(tb + j) * CCH;
            const f2 xr = *(const f2*)(xb + off);
            const f2 xi = *(const f2*)(xb + off + FHALF);
            const f2 hr = *(const f2*)(hb + off);
            const f2 hi = *(const f2*)(hb + off + FHALF);

            const f2 o0 = xr + winr;
            const f2 o1 = xi + wini;
            __builtin_nontemporal_store(o0, (f2*)(ob + off));
            __builtin_nontemporal_store(o1, (f2*)(ob + off + FHALF));

            const f2 ir = hr * xr - hi * xi;
            const f2 ii = hr * xi + hi * xr;

            winr += ir - histr[j];
            wini += ii - histi[j];
            histr[j] = ir; histi[j] = ii;
        }
    }

    // ---- Phase D: last 8 steps entirely from registers (no loads).
#pragma unroll
    for (int j = 0; j < WWIN; ++j) {
        const size_t off = (size_t)(t0 + TC - WWIN + j) * CCH;
        const f2 o0 = xtr[j] + winr;
        const f2 o1 = xti[j] + wini;
        __builtin_nontemporal_store(o0, (f2*)(ob + off));
        __builtin_nontemporal_store(o1, (f2*)(ob + off + FHALF));
        winr += itr[j] - histr[j];
        wini += iti[j] - histi[j];
    }
}

extern "C" void kernel_launch(void* const* d_in, const int* in_sizes, int n_in,
                              void* d_out, int out_size, void* d_ws, size_t ws_size,
                              hipStream_t stream) {
    const float* x = (const float*)d_in[0];
    const float* h = (const float*)d_in[1];
    float* out = (float*)d_out;

    const int total_cols = NB * NCHUNK;               // 4096 columns
    const int blocks     = total_cols / CPG;          // 512 blocks (4 waves each)
    isi_window_kernel<<<blocks, 256, 0, stream>>>(x, h, out);
}